// Round 1
// baseline (500.773 us; speedup 1.0000x reference)
//
#include <hip/hip_runtime.h>
#include <hip/hip_bf16.h>

#define BATCH 2
#define NQ 8192
#define DM 256
#define NH 8
#define NL 4
#define NP 4
#define DH 32
#define NTOK 21760

// ---------------- prep: Wqa = Wq @ Wa  [256,128], bqa = bq@Wa + ba ----------------
__global__ void prep_kernel(const float* __restrict__ Wq, const float* __restrict__ Wa,
                            const float* __restrict__ bq, const float* __restrict__ ba,
                            float* __restrict__ Wqa, float* __restrict__ bqa) {
    int i = blockIdx.x;      // 0..255 (query-feature dim)
    int j = threadIdx.x;     // 0..127 (logit dim)
    float acc = 0.f;
    for (int k = 0; k < 256; ++k)
        acc += Wq[i * 256 + k] * Wa[k * 128 + j];
    Wqa[i * 128 + j] = acc;
    if (i == 0) {
        float b = ba[j];
        for (int k = 0; k < 256; ++k)
            b += bq[k] * Wa[k * 128 + j];
        bqa[j] = b;
    }
}

// ---------------- generic fp32 tiled GEMM: C[M,N] = A[M,K]@W[K,N] + bias ----------------
// 64x64 tile, 256 threads, each thread 4x4, K-tile 16. N % 64 == 0, K % 16 == 0.
template <bool BF16OUT>
__global__ void gemm_bias_kernel(const float* __restrict__ A, const float* __restrict__ W,
                                 const float* __restrict__ bias, void* __restrict__ Cv,
                                 int M, int N, int K) {
    __shared__ float As[16][64];   // [k][m]
    __shared__ float Bs[16][64];   // [k][n]
    const int bm = blockIdx.y * 64;
    const int bn = blockIdx.x * 64;
    const int tid = threadIdx.x;
    const int tx = tid & 15;       // 0..15 -> n
    const int ty = tid >> 4;       // 0..15 -> m
    float acc[4][4] = {};
    for (int k0 = 0; k0 < K; k0 += 16) {
#pragma unroll
        for (int i = 0; i < 4; ++i) {
            int idx = tid + i * 256;         // 0..1023
            int m = idx >> 4, k = idx & 15;
            int gm = bm + m;
            As[k][m] = (gm < M) ? A[(size_t)gm * K + k0 + k] : 0.f;
        }
#pragma unroll
        for (int i = 0; i < 4; ++i) {
            int idx = tid + i * 256;
            int k = idx >> 6, n = idx & 63;
            Bs[k][n] = W[(size_t)(k0 + k) * N + bn + n];
        }
        __syncthreads();
#pragma unroll
        for (int k = 0; k < 16; ++k) {
            float a[4], b[4];
#pragma unroll
            for (int i = 0; i < 4; ++i) a[i] = As[k][ty * 4 + i];
#pragma unroll
            for (int j = 0; j < 4; ++j) b[j] = Bs[k][tx * 4 + j];
#pragma unroll
            for (int i = 0; i < 4; ++i)
#pragma unroll
                for (int j = 0; j < 4; ++j) acc[i][j] += a[i] * b[j];
        }
        __syncthreads();
    }
#pragma unroll
    for (int i = 0; i < 4; ++i) {
        int gm = bm + ty * 4 + i;
        if (gm >= M) continue;
#pragma unroll
        for (int j = 0; j < 4; ++j) {
            int gn = bn + tx * 4 + j;
            float val = acc[i][j] + bias[gn];
            if (BF16OUT)
                ((__hip_bfloat16*)Cv)[(size_t)gm * N + gn] = __float2bfloat16(val);
            else
                ((float*)Cv)[(size_t)gm * N + gn] = val;
        }
    }
}

// ---------------- attn: logits = query @ Wqa + bqa; softmax over P=4 ----------------
#define AROWS 8
__global__ void attn_kernel(const float* __restrict__ query, const float* __restrict__ Wqa,
                            const float* __restrict__ bqa, float* __restrict__ attn) {
    const int row0 = blockIdx.x * AROWS;   // 2048 blocks, 16384 rows
    const int tid = threadIdx.x;           // 128
    __shared__ float qs[AROWS][256];
    for (int i = tid; i < AROWS * 256; i += 128)
        qs[i >> 8][i & 255] = query[(size_t)row0 * 256 + i];
    __syncthreads();
    float acc[AROWS];
    const float b0 = bqa[tid];
#pragma unroll
    for (int r = 0; r < AROWS; ++r) acc[r] = b0;
    for (int k = 0; k < 256; ++k) {
        float w = Wqa[k * 128 + tid];
#pragma unroll
        for (int r = 0; r < AROWS; ++r) acc[r] += qs[r][k] * w;
    }
    __shared__ float lg[AROWS][128];
#pragma unroll
    for (int r = 0; r < AROWS; ++r) lg[r][tid] = acc[r];
    __syncthreads();
    const int g = tid & ~3;
#pragma unroll
    for (int r = 0; r < AROWS; ++r) {
        float m = fmaxf(fmaxf(lg[r][g], lg[r][g + 1]), fmaxf(lg[r][g + 2], lg[r][g + 3]));
        float e0 = __expf(lg[r][g] - m), e1 = __expf(lg[r][g + 1] - m);
        float e2 = __expf(lg[r][g + 2] - m), e3 = __expf(lg[r][g + 3] - m);
        float s = e0 + e1 + e2 + e3;
        attn[((size_t)(row0 + r)) * 128 + tid] = __expf(acc[r] - m) / s;
    }
}

// ---------------- sample: bilinear gather + attn-weighted sum ----------------
// one block per (b,q); 256 threads = 8 heads x 32 channels
__global__ void sample_kernel(const float* __restrict__ refp,   // [B,NQ,NL,2]
                              const float* __restrict__ sloc,   // [NH,NL,NP,2]
                              const __hip_bfloat16* __restrict__ v,  // [B,NTOK,256]
                              const float* __restrict__ attn,   // [B,NQ,128]
                              float* __restrict__ samp) {       // [B,NQ,256]
    const int bq = blockIdx.x;
    const int b = bq >> 13;     // NQ = 8192
    const int tid = threadIdx.x;
    const int h = tid >> 5, d = tid & 31;
    __shared__ float rp[NL * 2];
    __shared__ float at[NH * NL * NP];
    if (tid < NL * 2) rp[tid] = refp[(size_t)bq * NL * 2 + tid];
    if (tid < 128) at[tid] = attn[(size_t)bq * 128 + tid];
    __syncthreads();

    const __hip_bfloat16* vb = v + (size_t)b * NTOK * DM + h * DH + d;
    float acc = 0.f;
#pragma unroll
    for (int l = 0; l < NL; ++l) {
        const int HS[4] = {128, 64, 32, 16};
        const int SS[4] = {0, 16384, 20480, 21504};
        const int Wl = HS[l], Hl = HS[l];
        const __hip_bfloat16* vl = vb + (size_t)SS[l] * DM;
        const float rx = rp[l * 2 + 0], ry = rp[l * 2 + 1];
#pragma unroll
        for (int p = 0; p < NP; ++p) {
            const float sx = sloc[((h * NL + l) * NP + p) * 2 + 0];
            const float sy = sloc[((h * NL + l) * NP + p) * 2 + 1];
            // ix = ((2*(rx+sx)-1 + 1)*Wl - 1)*0.5 = (rx+sx)*Wl - 0.5
            const float ix = (rx + sx) * Wl - 0.5f;
            const float iy = (ry + sy) * Hl - 0.5f;
            const float x0f = floorf(ix), y0f = floorf(iy);
            const int x0 = (int)x0f, y0 = (int)y0f;
            const float wx1 = ix - x0f, wy1 = iy - y0f;
            const float wx0 = 1.f - wx1, wy0 = 1.f - wy1;
            const float a = at[h * 16 + l * 4 + p];
            float s = 0.f;
            const bool vx0 = (x0 >= 0) & (x0 < Wl);
            const bool vx1 = (x0 + 1 >= 0) & (x0 + 1 < Wl);
            const bool vy0 = (y0 >= 0) & (y0 < Hl);
            const bool vy1 = (y0 + 1 >= 0) & (y0 + 1 < Hl);
            if (vy0 & vx0) s += wy0 * wx0 * __bfloat162float(vl[(size_t)(y0 * Wl + x0) * DM]);
            if (vy0 & vx1) s += wy0 * wx1 * __bfloat162float(vl[(size_t)(y0 * Wl + x0 + 1) * DM]);
            if (vy1 & vx0) s += wy1 * wx0 * __bfloat162float(vl[(size_t)((y0 + 1) * Wl + x0) * DM]);
            if (vy1 & vx1) s += wy1 * wx1 * __bfloat162float(vl[(size_t)((y0 + 1) * Wl + x0 + 1) * DM]);
            acc += a * s;
        }
    }
    samp[(size_t)bq * DM + tid] = acc;
}

extern "C" void kernel_launch(void* const* d_in, const int* in_sizes, int n_in,
                              void* d_out, int out_size, void* d_ws, size_t ws_size,
                              hipStream_t stream) {
    const float* query  = (const float*)d_in[0];
    const float* refp   = (const float*)d_in[1];
    const float* inflat = (const float*)d_in[2];
    // d_in[3] spatial shapes (int64), d_in[4] level starts (int64): hardcoded constants
    const float* Wq = (const float*)d_in[5];
    const float* bq = (const float*)d_in[6];
    const float* Wv = (const float*)d_in[7];
    const float* bv = (const float*)d_in[8];
    const float* Wa = (const float*)d_in[9];
    const float* ba = (const float*)d_in[10];
    const float* sloc = (const float*)d_in[11];
    const float* Wo = (const float*)d_in[12];
    const float* bo = (const float*)d_in[13];
    float* out = (float*)d_out;

    char* ws = (char*)d_ws;
    float* Wqa = (float*)(ws + 0);                       // 131072 B
    float* bqa = (float*)(ws + 131072);                  // 512 B
    __hip_bfloat16* v = (__hip_bfloat16*)(ws + (1u << 20));   // 22,282,240 B
    float* attn = (float*)(ws + (24u << 20));            // 8,388,608 B
    float* samp = (float*)(ws + (32u << 20));            // 16,777,216 B  (ends ~48MB)

    prep_kernel<<<256, 128, 0, stream>>>(Wq, Wa, bq, ba, Wqa, bqa);
    // v = input_flatten @ Wv + bv  (M=43520, N=256, K=256) -> bf16
    gemm_bias_kernel<true><<<dim3(4, 680), 256, 0, stream>>>(inflat, Wv, bv, v, BATCH * NTOK, 256, 256);
    attn_kernel<<<(BATCH * NQ) / AROWS, 128, 0, stream>>>(query, Wqa, bqa, attn);
    sample_kernel<<<BATCH * NQ, 256, 0, stream>>>(refp, sloc, v, attn, samp);
    // out = samp @ Wo + bo  (M=16384, N=256, K=256) -> fp32
    gemm_bias_kernel<false><<<dim3(4, 256), 256, 0, stream>>>(samp, Wo, bo, out, BATCH * NQ, 256, 256);
}

// Round 2
// 241.933 us; speedup vs baseline: 2.0699x; 2.0699x over previous
//
#include <hip/hip_runtime.h>
#include <hip/hip_bf16.h>

#define BATCH 2
#define NQ 8192
#define DM 256
#define NH 8
#define NL 4
#define NP 4
#define DH 32
#define NTOK 21760

typedef __attribute__((ext_vector_type(4))) float f32x4;
typedef __attribute__((ext_vector_type(8))) short s16x8;

static __device__ __forceinline__ unsigned short f2bu(float x) {
    __hip_bfloat16 h = __float2bfloat16(x);
    return __builtin_bit_cast(unsigned short, h);
}

// ---------------- prep: Wqa = Wq@Wa [256,128], bqa; WvT/WoT = bf16 transposes ----------------
__global__ void prep_kernel(const float* __restrict__ Wq, const float* __restrict__ Wa,
                            const float* __restrict__ bq, const float* __restrict__ ba,
                            const float* __restrict__ Wv, const float* __restrict__ Wo,
                            float* __restrict__ Wqa, float* __restrict__ bqa,
                            unsigned short* __restrict__ WvT, unsigned short* __restrict__ WoT) {
    const int i = blockIdx.x;    // 0..255
    const int j = threadIdx.x;   // 0..255
    WvT[j * 256 + i] = f2bu(Wv[i * 256 + j]);
    WoT[j * 256 + i] = f2bu(Wo[i * 256 + j]);
    if (j < 128) {
        float acc = 0.f;
        for (int k = 0; k < 256; ++k) acc += Wq[i * 256 + k] * Wa[k * 128 + j];
        Wqa[i * 128 + j] = acc;
        if (i == 0) {
            float bacc = ba[j];
            for (int k = 0; k < 256; ++k) bacc += bq[k] * Wa[k * 128 + j];
            bqa[j] = bacc;
        }
    }
}

// ---------------- MFMA bf16 GEMM: C[M,N] = A[M,K] @ Bt[N,K]^T + bias ----------------
// BM=BN=128, BK=64, 256 threads (4 waves, 2x2), mfma_f32_16x16x32_bf16.
// LDS XOR-swizzle: byte ^= (row&7)<<4 (applied identically on write and read).
template <bool AFP32, bool BF16OUT>
__global__ __launch_bounds__(256) void gemm_mfma(
    const void* __restrict__ Av, const unsigned short* __restrict__ Bt,
    const float* __restrict__ bias, void* __restrict__ Cv,
    int M, int N, int K) {
    __shared__ __align__(16) char As[128 * 64 * 2];
    __shared__ __align__(16) char Bs[128 * 64 * 2];
    const int tid = threadIdx.x;
    const int lane = tid & 63;
    const int wave = tid >> 6;
    const int wr = wave >> 1, wc = wave & 1;
    const int bm = blockIdx.y * 128;
    const int bn = blockIdx.x * 128;

    f32x4 acc[4][4] = {};

    const int srow = tid >> 3;        // 0..31 (+32 per round)
    const int skc = (tid & 7) * 8;    // k-offset in elems (0..56)

    for (int k0 = 0; k0 < K; k0 += 64) {
#pragma unroll
        for (int r = 0; r < 4; ++r) {
            const int row = srow + r * 32;
            const int byte = (row * 128 + skc * 2) ^ ((row & 7) << 4);
            s16x8 av;
            if (AFP32) {
                const float* Af = (const float*)Av + (size_t)(bm + row) * K + k0 + skc;
                const float4 f0 = *(const float4*)(Af);
                const float4 f1 = *(const float4*)(Af + 4);
                av[0] = (short)f2bu(f0.x); av[1] = (short)f2bu(f0.y);
                av[2] = (short)f2bu(f0.z); av[3] = (short)f2bu(f0.w);
                av[4] = (short)f2bu(f1.x); av[5] = (short)f2bu(f1.y);
                av[6] = (short)f2bu(f1.z); av[7] = (short)f2bu(f1.w);
            } else {
                av = *(const s16x8*)((const unsigned short*)Av + (size_t)(bm + row) * K + k0 + skc);
            }
            *(s16x8*)(As + byte) = av;
            const s16x8 bv = *(const s16x8*)(Bt + (size_t)(bn + row) * K + k0 + skc);
            *(s16x8*)(Bs + byte) = bv;
        }
        __syncthreads();
#pragma unroll
        for (int f = 0; f < 2; ++f) {
            s16x8 a[4], b[4];
#pragma unroll
            for (int i = 0; i < 4; ++i) {
                const int arow = wr * 64 + i * 16 + (lane & 15);
                const int abyte = (arow * 128 + f * 64 + (lane >> 4) * 16) ^ ((arow & 7) << 4);
                a[i] = *(const s16x8*)(As + abyte);
                const int brow = wc * 64 + i * 16 + (lane & 15);
                const int bbyte = (brow * 128 + f * 64 + (lane >> 4) * 16) ^ ((brow & 7) << 4);
                b[i] = *(const s16x8*)(Bs + bbyte);
            }
#pragma unroll
            for (int i = 0; i < 4; ++i)
#pragma unroll
                for (int j = 0; j < 4; ++j)
                    acc[i][j] = __builtin_amdgcn_mfma_f32_16x16x32_bf16(a[i], b[j], acc[i][j], 0, 0, 0);
        }
        __syncthreads();
    }

#pragma unroll
    for (int i = 0; i < 4; ++i) {
        const int row0 = bm + wr * 64 + i * 16 + (lane >> 4) * 4;
#pragma unroll
        for (int j = 0; j < 4; ++j) {
            const int col = bn + wc * 64 + j * 16 + (lane & 15);
            const float bsv = bias[col];
#pragma unroll
            for (int q = 0; q < 4; ++q) {
                const float val = acc[i][j][q] + bsv;
                if (BF16OUT)
                    ((unsigned short*)Cv)[(size_t)(row0 + q) * N + col] = f2bu(val);
                else
                    ((float*)Cv)[(size_t)(row0 + q) * N + col] = val;
            }
        }
    }
}

// ---------------- attn: logits = query @ Wqa + bqa; softmax over P=4 ----------------
#define AROWS 8
__global__ void attn_kernel(const float* __restrict__ query, const float* __restrict__ Wqa,
                            const float* __restrict__ bqa, float* __restrict__ attn) {
    const int row0 = blockIdx.x * AROWS;
    const int tid = threadIdx.x;  // 128
    __shared__ float qs[AROWS][256];
    for (int i = tid; i < AROWS * 256; i += 128)
        qs[i >> 8][i & 255] = query[(size_t)row0 * 256 + i];
    __syncthreads();
    float acc[AROWS];
    const float b0 = bqa[tid];
#pragma unroll
    for (int r = 0; r < AROWS; ++r) acc[r] = b0;
    for (int k = 0; k < 256; ++k) {
        const float w = Wqa[k * 128 + tid];
#pragma unroll
        for (int r = 0; r < AROWS; ++r) acc[r] += qs[r][k] * w;
    }
    __shared__ float lg[AROWS][128];
#pragma unroll
    for (int r = 0; r < AROWS; ++r) lg[r][tid] = acc[r];
    __syncthreads();
    const int g = tid & ~3;
#pragma unroll
    for (int r = 0; r < AROWS; ++r) {
        const float m = fmaxf(fmaxf(lg[r][g], lg[r][g + 1]), fmaxf(lg[r][g + 2], lg[r][g + 3]));
        const float e0 = __expf(lg[r][g] - m), e1 = __expf(lg[r][g + 1] - m);
        const float e2 = __expf(lg[r][g + 2] - m), e3 = __expf(lg[r][g + 3] - m);
        attn[((size_t)(row0 + r)) * 128 + tid] = __expf(acc[r] - m) / (e0 + e1 + e2 + e3);
    }
}

// ---------------- sample: bilinear gather + attn-weighted sum (bf16 v, 2ch/lane) ----------------
// 256 threads = 2 queries x (8 heads x 16 dword-lanes). Output samp in bf16.
__global__ __launch_bounds__(256) void sample_kernel(
    const float* __restrict__ refp, const float* __restrict__ sloc,
    const unsigned int* __restrict__ v,    // bf16 pairs: [B][NTOK][128]
    const float* __restrict__ attn,        // [B*NQ][128]
    unsigned int* __restrict__ samp) {     // bf16 pairs: [B*NQ][128]
    const int tid = threadIdx.x;
    const int q0 = blockIdx.x * 2;
    const int qi = tid >> 7;
    const int sub = tid & 127;
    const int h = sub >> 4;
    const int dp = sub & 15;
    const int bq = q0 + qi;
    const int b = bq >> 13;  // NQ=8192

    __shared__ float sl[NH][NL][NP][2];  // sloc*Wl - 0.5
    __shared__ float rp[2][NL * 2];
    __shared__ float at[2][128];

    {
        const int c = tid & 1, p = (tid >> 1) & 3, l = (tid >> 3) & 3, hh = tid >> 5;
        const float scale = (float)(128 >> l);
        sl[hh][l][p][c] = sloc[((hh * NL + l) * NP + p) * 2 + c] * scale - 0.5f;
    }
    if (tid < 16) rp[tid >> 3][tid & 7] = refp[(size_t)q0 * 8 + tid];
    at[qi][sub] = attn[(size_t)bq * 128 + sub];
    __syncthreads();

    const int vq = b * (NTOK * 128) + h * 16 + dp;
    float acc0 = 0.f, acc1 = 0.f;
    const int WLs[4] = {128, 64, 32, 16};
    const int SSs[4] = {0, 16384, 20480, 21504};
#pragma unroll
    for (int l = 0; l < NL; ++l) {
        const int Wl = WLs[l];
        const float fW = (float)Wl;
        const int base = vq + SSs[l] * 128;
        const float rx = rp[qi][l * 2], ry = rp[qi][l * 2 + 1];
#pragma unroll
        for (int p = 0; p < NP; ++p) {
            const float ix = fmaf(rx, fW, sl[h][l][p][0]);
            const float iy = fmaf(ry, fW, sl[h][l][p][1]);
            const float xf = floorf(ix), yf = floorf(iy);
            const int x0 = (int)xf, y0 = (int)yf;
            const int x1 = x0 + 1, y1 = y0 + 1;
            float wx1 = ix - xf, wy1 = iy - yf;
            float wx0 = 1.f - wx1, wy0 = 1.f - wy1;
            const float a = at[qi][h * 16 + l * 4 + p];
            wx0 = ((unsigned)x0 < (unsigned)Wl) ? wx0 : 0.f;
            wx1 = ((unsigned)x1 < (unsigned)Wl) ? wx1 : 0.f;
            wy0 = ((unsigned)y0 < (unsigned)Wl) ? wy0 * a : 0.f;
            wy1 = ((unsigned)y1 < (unsigned)Wl) ? wy1 * a : 0.f;
            const int x0c = min(max(x0, 0), Wl - 1);
            const int x1c = min(max(x1, 0), Wl - 1);
            const int y0c = min(max(y0, 0), Wl - 1);
            const int y1c = min(max(y1, 0), Wl - 1);
            const int r0 = y0c * Wl, r1 = y1c * Wl;
            const unsigned int u00 = v[base + (r0 + x0c) * 128];
            const unsigned int u01 = v[base + (r0 + x1c) * 128];
            const unsigned int u10 = v[base + (r1 + x0c) * 128];
            const unsigned int u11 = v[base + (r1 + x1c) * 128];
            const float w00 = wy0 * wx0, w01 = wy0 * wx1;
            const float w10 = wy1 * wx0, w11 = wy1 * wx1;
            acc0 = fmaf(__uint_as_float(u00 << 16), w00, acc0);
            acc1 = fmaf(__uint_as_float(u00 & 0xffff0000u), w00, acc1);
            acc0 = fmaf(__uint_as_float(u01 << 16), w01, acc0);
            acc1 = fmaf(__uint_as_float(u01 & 0xffff0000u), w01, acc1);
            acc0 = fmaf(__uint_as_float(u10 << 16), w10, acc0);
            acc1 = fmaf(__uint_as_float(u10 & 0xffff0000u), w10, acc1);
            acc0 = fmaf(__uint_as_float(u11 << 16), w11, acc0);
            acc1 = fmaf(__uint_as_float(u11 & 0xffff0000u), w11, acc1);
        }
    }
    const unsigned int us = (unsigned int)f2bu(acc0) | ((unsigned int)f2bu(acc1) << 16);
    samp[(size_t)bq * 128 + h * 16 + dp] = us;
}

extern "C" void kernel_launch(void* const* d_in, const int* in_sizes, int n_in,
                              void* d_out, int out_size, void* d_ws, size_t ws_size,
                              hipStream_t stream) {
    const float* query  = (const float*)d_in[0];
    const float* refp   = (const float*)d_in[1];
    const float* inflat = (const float*)d_in[2];
    const float* Wq = (const float*)d_in[5];
    const float* bq = (const float*)d_in[6];
    const float* Wv = (const float*)d_in[7];
    const float* bv = (const float*)d_in[8];
    const float* Wa = (const float*)d_in[9];
    const float* ba = (const float*)d_in[10];
    const float* sloc = (const float*)d_in[11];
    const float* Wo = (const float*)d_in[12];
    const float* bo = (const float*)d_in[13];
    float* out = (float*)d_out;

    char* ws = (char*)d_ws;
    float* Wqa = (float*)(ws + 0);                          // 128 KB
    float* bqa = (float*)(ws + (128u << 10));               // 512 B
    unsigned short* WvT = (unsigned short*)(ws + (192u << 10));  // 128 KB
    unsigned short* WoT = (unsigned short*)(ws + (320u << 10));  // 128 KB
    unsigned int* vbuf = (unsigned int*)(ws + (1u << 20));  // 22.3 MB bf16 [B][NTOK][256]
    float* attn = (float*)(ws + (24u << 20));               // 8 MB
    unsigned int* samp = (unsigned int*)(ws + (32u << 20)); // 8 MB bf16 [B*NQ][256] -> ends 40MB

    prep_kernel<<<256, 256, 0, stream>>>(Wq, Wa, bq, ba, Wv, Wo, Wqa, bqa, WvT, WoT);
    // v = inflat @ Wv + bv   (M=43520, N=256, K=256), A fp32 on-the-fly cvt, out bf16
    gemm_mfma<true, true><<<dim3(2, 340), 256, 0, stream>>>(inflat, WvT, bv, vbuf, BATCH * NTOK, 256, 256);
    attn_kernel<<<(BATCH * NQ) / AROWS, 128, 0, stream>>>(query, Wqa, bqa, attn);
    sample_kernel<<<BATCH * NQ / 2, 256, 0, stream>>>(refp, sloc, (const unsigned int*)vbuf, attn, samp);
    // out = samp @ Wo + bo   (M=16384, N=256, K=256), A bf16, out fp32
    gemm_mfma<false, false><<<dim3(2, 128), 256, 0, stream>>>(samp, WoT, bo, out, BATCH * NQ, 256, 256);
}

// Round 3
// 206.834 us; speedup vs baseline: 2.4211x; 1.1697x over previous
//
#include <hip/hip_runtime.h>
#include <hip/hip_bf16.h>

#define BATCH 2
#define NQ 8192
#define NTOK 21760

typedef __attribute__((ext_vector_type(4))) float f32x4;
typedef __attribute__((ext_vector_type(8))) short s16x8;

static __device__ __forceinline__ unsigned short f2bu(float x) {
    __hip_bfloat16 h = __float2bfloat16(x);
    return __builtin_bit_cast(unsigned short, h);
}
static __device__ __forceinline__ float blo(unsigned int u) { return __uint_as_float(u << 16); }
static __device__ __forceinline__ float bhi(unsigned int u) { return __uint_as_float(u & 0xffff0000u); }

// ---------------- wqa: WqaT[j][i] = bf16( (Wq@Wa)[i][j] ), bqa = bq@Wa + ba ----------------
__global__ void wqa_kernel(const float* __restrict__ Wq, const float* __restrict__ Wa,
                           const float* __restrict__ bq, const float* __restrict__ ba,
                           unsigned short* __restrict__ WqaT, float* __restrict__ bqa) {
    const int i = blockIdx.x;   // 0..255
    const int j = threadIdx.x;  // 0..127
    float acc = 0.f;
#pragma unroll 8
    for (int k = 0; k < 256; ++k) acc += Wq[i * 256 + k] * Wa[k * 128 + j];
    WqaT[j * 256 + i] = f2bu(acc);
    if (i == 0) {
        float b = ba[j];
#pragma unroll 8
        for (int k = 0; k < 256; ++k) b += bq[k] * Wa[k * 128 + j];
        bqa[j] = b;
    }
}

// ---------------- transpose 256x256 fp32 -> bf16 transposed (Wv, Wo) ----------------
__global__ __launch_bounds__(256) void transpose_kernel(const float* __restrict__ Wv, const float* __restrict__ Wo,
                                                        unsigned short* __restrict__ WvT, unsigned short* __restrict__ WoT) {
    __shared__ float t[32][33];
    const int bid = blockIdx.x;  // 0..127
    const int mat = bid >> 6;
    const int tile = bid & 63;
    const int i0 = (tile >> 3) * 32, j0 = (tile & 7) * 32;
    const float* src = mat ? Wo : Wv;
    unsigned short* dst = mat ? WoT : WvT;
    const int tx = threadIdx.x & 31, ty = threadIdx.x >> 5;
#pragma unroll
    for (int r = 0; r < 4; ++r)
        t[ty + 8 * r][tx] = src[(i0 + ty + 8 * r) * 256 + j0 + tx];
    __syncthreads();
#pragma unroll
    for (int r = 0; r < 4; ++r)
        dst[(j0 + ty + 8 * r) * 256 + i0 + tx] = f2bu(t[tx][ty + 8 * r]);
}

// ---------------- MFMA bf16 GEMM: C[M,N] = A[M,K=256] @ Bt[N,K]^T + bias ----------------
// 256 threads, 4 waves (WRN x WCN). Single-LDS-buffer with next-tile register prefetch (T14).
template <int BM, int BN, int WRN, int WCN, bool AFP32, bool BF16OUT>
__global__ __launch_bounds__(256) void gemm_mfma(
    const void* __restrict__ Av, const unsigned short* __restrict__ Bt,
    const float* __restrict__ bias, void* __restrict__ Cv, int N) {
    constexpr int K = 256, NT = 4;
    constexpr int IM = BM / (WRN * 16);
    constexpr int JN = BN / (WCN * 16);
    constexpr int RA = BM / 32;
    constexpr int RB = BN / 32;
    __shared__ __align__(16) char As[BM * 128];
    __shared__ __align__(16) char Bs[BN * 128];
    const int tid = threadIdx.x;
    const int lane = tid & 63;
    const int wave = tid >> 6;
    const int wr = wave / WCN, wc = wave % WCN;
    const int bm = blockIdx.y * BM, bn = blockIdx.x * BN;
    const int srow = tid >> 3;        // 0..31
    const int skc = (tid & 7) * 8;    // k elem offset 0..56

    f32x4 acc[IM][JN] = {};
    float4 af0[2][RA], af1[2][RA];
    s16x8 ab[2][RA], bb[2][RB];

    auto loadT = [&](int t, int buf) {
        const int k0 = t * 64;
#pragma unroll
        for (int r = 0; r < RA; ++r) {
            const int row = bm + srow + r * 32;
            if constexpr (AFP32) {
                const float* Af = (const float*)Av + (size_t)row * K + k0 + skc;
                af0[buf][r] = *(const float4*)Af;
                af1[buf][r] = *(const float4*)(Af + 4);
            } else {
                ab[buf][r] = *(const s16x8*)((const unsigned short*)Av + (size_t)row * K + k0 + skc);
            }
        }
#pragma unroll
        for (int r = 0; r < RB; ++r) {
            const int row = bn + srow + r * 32;
            bb[buf][r] = *(const s16x8*)(Bt + (size_t)row * K + k0 + skc);
        }
    };
    auto writeT = [&](int buf) {
#pragma unroll
        for (int r = 0; r < RA; ++r) {
            const int row = srow + r * 32;
            const int byte = (row * 128 + skc * 2) ^ ((row & 7) << 4);
            s16x8 av;
            if constexpr (AFP32) {
                const float4 f0 = af0[buf][r], f1 = af1[buf][r];
                av[0] = (short)f2bu(f0.x); av[1] = (short)f2bu(f0.y);
                av[2] = (short)f2bu(f0.z); av[3] = (short)f2bu(f0.w);
                av[4] = (short)f2bu(f1.x); av[5] = (short)f2bu(f1.y);
                av[6] = (short)f2bu(f1.z); av[7] = (short)f2bu(f1.w);
            } else {
                av = ab[buf][r];
            }
            *(s16x8*)(As + byte) = av;
        }
#pragma unroll
        for (int r = 0; r < RB; ++r) {
            const int row = srow + r * 32;
            const int byte = (row * 128 + skc * 2) ^ ((row & 7) << 4);
            *(s16x8*)(Bs + byte) = bb[buf][r];
        }
    };

    loadT(0, 0);
#pragma unroll
    for (int t = 0; t < NT; ++t) {
        if (t) __syncthreads();
        writeT(t & 1);
        if (t + 1 < NT) loadT(t + 1, (t + 1) & 1);   // in flight during compute
        __syncthreads();
#pragma unroll
        for (int f = 0; f < 2; ++f) {
            s16x8 a[IM], b[JN];
#pragma unroll
            for (int i = 0; i < IM; ++i) {
                const int arow = wr * (IM * 16) + i * 16 + (lane & 15);
                const int abyte = (arow * 128 + f * 64 + (lane >> 4) * 16) ^ ((arow & 7) << 4);
                a[i] = *(const s16x8*)(As + abyte);
            }
#pragma unroll
            for (int j = 0; j < JN; ++j) {
                const int brow = wc * (JN * 16) + j * 16 + (lane & 15);
                const int bbyte = (brow * 128 + f * 64 + (lane >> 4) * 16) ^ ((brow & 7) << 4);
                b[j] = *(const s16x8*)(Bs + bbyte);
            }
#pragma unroll
            for (int i = 0; i < IM; ++i)
#pragma unroll
                for (int j = 0; j < JN; ++j)
                    acc[i][j] = __builtin_amdgcn_mfma_f32_16x16x32_bf16(a[i], b[j], acc[i][j], 0, 0, 0);
        }
    }

#pragma unroll
    for (int i = 0; i < IM; ++i) {
        const int row0 = bm + wr * (IM * 16) + i * 16 + (lane >> 4) * 4;
#pragma unroll
        for (int j = 0; j < JN; ++j) {
            const int col = bn + wc * (JN * 16) + j * 16 + (lane & 15);
            const float bsv = bias[col];
#pragma unroll
            for (int q = 0; q < 4; ++q) {
                const float val = acc[i][j][q] + bsv;
                if constexpr (BF16OUT)
                    ((unsigned short*)Cv)[(size_t)(row0 + q) * N + col] = f2bu(val);
                else
                    ((float*)Cv)[(size_t)(row0 + q) * N + col] = val;
            }
        }
    }
}

// ---------------- sample: fused softmax + bilinear gather, two-phase ----------------
// Block = 4 queries. Phase 1: 512 point-slots -> softmax(shfl) + indices/weights into LDS.
// Phase 2: 256 threads = 4q x 8h x 8 lanes, 4 channels/lane via dwordx2 loads.
__global__ __launch_bounds__(256) void sample_kernel(
    const float* __restrict__ refp, const float* __restrict__ sloc,
    const unsigned int* __restrict__ v,      // bf16 pairs [B][NTOK][128]
    const float* __restrict__ logits,        // [B*NQ][128]
    unsigned int* __restrict__ samp) {       // bf16 pairs [B*NQ][128]
    const int tid = threadIdx.x;
    const int q0 = blockIdx.x * 4;
    __shared__ int4 metaI[512];
    __shared__ float4 metaW[512];
    __shared__ float slc[256];
    __shared__ float lgs[512];
    __shared__ float rps[32];

    {
        const int l = (tid >> 3) & 3;  // sloc layout [h][l][p][c]: c=b0, p=b1-2, l=b3-4, h=b5-7
        slc[tid] = sloc[tid] * (float)(128 >> l) - 0.5f;
    }
    lgs[tid] = logits[(size_t)q0 * 128 + tid];
    lgs[tid + 256] = logits[(size_t)q0 * 128 + tid + 256];
    if (tid < 32) rps[tid] = refp[(size_t)q0 * 8 + tid];
    __syncthreads();

#pragma unroll
    for (int ss = 0; ss < 2; ++ss) {
        const int h = tid & 7;
        const int p = (tid >> 3) & 3;
        const int l = (tid >> 5) & 3;
        const int qi = (tid >> 7) + ss * 2;
        const int lp = l * 4 + p;
        const int bq = q0 + qi;
        const int b = bq >> 13;  // NQ=8192
        const int Wl = 128 >> l;
        // softmax over p (partners at lane^8, lane^16 share qi,h,l)
        const float lg = lgs[qi * 128 + h * 16 + lp];
        float m = fmaxf(lg, __shfl_xor(lg, 8));
        m = fmaxf(m, __shfl_xor(m, 16));
        const float e = __expf(lg - m);
        float sum = e + __shfl_xor(e, 8);
        sum += __shfl_xor(sum, 16);
        const float a = e / sum;
        // bilinear setup
        const float fW = (float)Wl;
        const float ix = fmaf(rps[qi * 8 + l * 2 + 0], fW, slc[h * 32 + l * 8 + p * 2 + 0]);
        const float iy = fmaf(rps[qi * 8 + l * 2 + 1], fW, slc[h * 32 + l * 8 + p * 2 + 1]);
        const float xf = floorf(ix), yf = floorf(iy);
        const int x0 = (int)xf, y0 = (int)yf;
        const int x1 = x0 + 1, y1 = y0 + 1;
        float wx1 = ix - xf, wy1 = iy - yf;
        float wx0 = 1.f - wx1, wy0 = 1.f - wy1;
        wx0 = ((unsigned)x0 < (unsigned)Wl) ? wx0 : 0.f;
        wx1 = ((unsigned)x1 < (unsigned)Wl) ? wx1 : 0.f;
        wy0 = ((unsigned)y0 < (unsigned)Wl) ? wy0 * a : 0.f;
        wy1 = ((unsigned)y1 < (unsigned)Wl) ? wy1 * a : 0.f;
        const int x0c = min(max(x0, 0), Wl - 1);
        const int x1c = min(max(x1, 0), Wl - 1);
        const int y0c = min(max(y0, 0), Wl - 1);
        const int y1c = min(max(y1, 0), Wl - 1);
        // level start: SS(l) = (65536 - 65536>>(2l)) / 3
        const int SS = (65536 - (65536 >> (2 * l))) / 3;
        const int base = b * (NTOK * 128) + SS * 128 + h * 16;
        const int r0 = y0c * Wl, r1 = y1c * Wl;
        const int s = lp * 32 + qi * 8 + h;
        metaI[s] = make_int4(base + (r0 + x0c) * 128, base + (r0 + x1c) * 128,
                             base + (r1 + x0c) * 128, base + (r1 + x1c) * 128);
        metaW[s] = make_float4(wy0 * wx0, wy0 * wx1, wy1 * wx0, wy1 * wx1);
    }
    __syncthreads();

    const int qi = tid >> 6, h = (tid >> 3) & 7, c = tid & 7;
    const unsigned int* vp = v + c * 2;
    float a0 = 0.f, a1 = 0.f, a2 = 0.f, a3 = 0.f;
#pragma unroll
    for (int lp = 0; lp < 16; ++lp) {
        const int s = lp * 32 + qi * 8 + h;
        const int4 I = metaI[s];
        const float4 W = metaW[s];
        uint2 u;
        u = *(const uint2*)(vp + I.x);
        a0 = fmaf(blo(u.x), W.x, a0); a1 = fmaf(bhi(u.x), W.x, a1);
        a2 = fmaf(blo(u.y), W.x, a2); a3 = fmaf(bhi(u.y), W.x, a3);
        u = *(const uint2*)(vp + I.y);
        a0 = fmaf(blo(u.x), W.y, a0); a1 = fmaf(bhi(u.x), W.y, a1);
        a2 = fmaf(blo(u.y), W.y, a2); a3 = fmaf(bhi(u.y), W.y, a3);
        u = *(const uint2*)(vp + I.z);
        a0 = fmaf(blo(u.x), W.z, a0); a1 = fmaf(bhi(u.x), W.z, a1);
        a2 = fmaf(blo(u.y), W.z, a2); a3 = fmaf(bhi(u.y), W.z, a3);
        u = *(const uint2*)(vp + I.w);
        a0 = fmaf(blo(u.x), W.w, a0); a1 = fmaf(bhi(u.x), W.w, a1);
        a2 = fmaf(blo(u.y), W.w, a2); a3 = fmaf(bhi(u.y), W.w, a3);
    }
    const int bq = q0 + qi;
    uint2 o;
    o.x = (unsigned)f2bu(a0) | ((unsigned)f2bu(a1) << 16);
    o.y = (unsigned)f2bu(a2) | ((unsigned)f2bu(a3) << 16);
    *(uint2*)(samp + (size_t)bq * 128 + h * 16 + c * 2) = o;
}

extern "C" void kernel_launch(void* const* d_in, const int* in_sizes, int n_in,
                              void* d_out, int out_size, void* d_ws, size_t ws_size,
                              hipStream_t stream) {
    const float* query  = (const float*)d_in[0];
    const float* refp   = (const float*)d_in[1];
    const float* inflat = (const float*)d_in[2];
    const float* Wq = (const float*)d_in[5];
    const float* bq = (const float*)d_in[6];
    const float* Wv = (const float*)d_in[7];
    const float* bv = (const float*)d_in[8];
    const float* Wa = (const float*)d_in[9];
    const float* ba = (const float*)d_in[10];
    const float* sloc = (const float*)d_in[11];
    const float* Wo = (const float*)d_in[12];
    const float* bo = (const float*)d_in[13];
    float* out = (float*)d_out;

    char* ws = (char*)d_ws;
    unsigned short* WqaT = (unsigned short*)(ws + 0);            // 64 KB  [128][256] bf16
    float* bqa = (float*)(ws + (64u << 10));                     // 512 B
    unsigned short* WvT = (unsigned short*)(ws + (128u << 10));  // 128 KB [256][256] bf16
    unsigned short* WoT = (unsigned short*)(ws + (256u << 10));  // 128 KB
    unsigned int* vbuf = (unsigned int*)(ws + (1u << 20));       // 22.3 MB bf16 [B][NTOK][256]
    float* logits = (float*)(ws + (24u << 20));                  // 8 MB fp32 [B*NQ][128]
    unsigned int* samp = (unsigned int*)(ws + (32u << 20));      // 8 MB bf16 [B*NQ][256]

    wqa_kernel<<<256, 128, 0, stream>>>(Wq, Wa, bq, ba, WqaT, bqa);
    transpose_kernel<<<128, 256, 0, stream>>>(Wv, Wo, WvT, WoT);
    // v = inflat @ Wv + bv   (M=43520, N=256) -> bf16
    gemm_mfma<128, 128, 2, 2, true, true><<<dim3(2, 340), 256, 0, stream>>>(inflat, WvT, bv, vbuf, 256);
    // logits = query @ Wqa + bqa   (M=16384, N=128) -> fp32
    gemm_mfma<64, 64, 2, 2, true, false><<<dim3(2, 256), 256, 0, stream>>>(query, WqaT, bqa, logits, 128);
    sample_kernel<<<BATCH * NQ / 4, 256, 0, stream>>>(refp, sloc, (const unsigned int*)vbuf, logits, samp);
    // out = samp @ Wo + bo   (M=16384, N=256) -> fp32
    gemm_mfma<64, 128, 1, 4, false, false><<<dim3(2, 256), 256, 0, stream>>>(samp, WoT, bo, out, 256);
}